// Round 17
// baseline (463.296 us; speedup 1.0000x reference)
//
#include <hip/hip_runtime.h>
#include <hip/hip_bf16.h>
#include <math.h>

#define N_EMBED 1024
#define N_HEAD 16
#define HD 64
#define BB 4
#define TT 2048
#define NTOK (BB * TT)        // 8192 rows
#define QKV_LD (3 * N_EMBED)  // 3072

typedef __bf16 bf16x8 __attribute__((ext_vector_type(8)));
typedef float f32x4 __attribute__((ext_vector_type(4)));

__device__ __forceinline__ unsigned short f2bf(float f) {
    __hip_bfloat16 h = __float2bfloat16(f);
    return __builtin_bit_cast(unsigned short, h);
}

// async global->LDS, 16B per lane. LDS dest = wave-uniform base + lane*16.
__device__ __forceinline__ void gll16(const unsigned short* g, unsigned short* l) {
    __builtin_amdgcn_global_load_lds(
        (const __attribute__((address_space(1))) void*)g,
        (__attribute__((address_space(3))) void*)l,
        16, 0, 0);
}

// ---------------------------------------------------------------------------
// Weight transpose + fp32 -> bf16 convert:  in [K][N] fp32  ->  out [N][K] bf16
// ---------------------------------------------------------------------------
__global__ __launch_bounds__(256) void transpose_bf16_kernel(
    const float* __restrict__ in, unsigned short* __restrict__ out, int K, int N) {
    __shared__ float tile[32][33];
    int bx = blockIdx.x * 32;  // n base
    int by = blockIdx.y * 32;  // k base
    int tx = threadIdx.x, ty = threadIdx.y;
#pragma unroll
    for (int i = ty; i < 32; i += 8)
        tile[i][tx] = in[(size_t)(by + i) * N + bx + tx];
    __syncthreads();
#pragma unroll
    for (int i = ty; i < 32; i += 8)
        out[(size_t)(bx + i) * K + by + tx] = f2bf(tile[tx][i]);
}

// ---------------------------------------------------------------------------
// V transpose: qkv [B*T][3072] (v at col 2048+h*64) -> vt [b*16+h][64][2048]
// ---------------------------------------------------------------------------
__global__ __launch_bounds__(256) void transpose_v_kernel(
    const unsigned short* __restrict__ qkv, unsigned short* __restrict__ vt) {
    __shared__ unsigned short tile[32][33];
    int z = blockIdx.z;
    int b = z >> 4, h = z & 15;
    int t0 = blockIdx.x * 32, d0 = blockIdx.y * 32;
    int tx = threadIdx.x, ty = threadIdx.y;
    const unsigned short* src = qkv + (size_t)(b * TT) * QKV_LD + 2 * N_EMBED + h * HD;
#pragma unroll
    for (int i = ty; i < 32; i += 8)
        tile[i][tx] = src[(size_t)(t0 + i) * QKV_LD + d0 + tx];
    __syncthreads();
    unsigned short* dst = vt + (size_t)z * HD * TT;
#pragma unroll
    for (int i = ty; i < 32; i += 8)
        dst[(size_t)(d0 + i) * TT + t0 + tx] = tile[tx][i];
}

// ---------------------------------------------------------------------------
// Row LayerNorm: fp32 in [rows][1024] -> bf16 out
// ---------------------------------------------------------------------------
__global__ __launch_bounds__(256) void ln_kernel(
    const float* __restrict__ x, const float* __restrict__ w,
    const float* __restrict__ b, unsigned short* __restrict__ out) {
    int row = blockIdx.x;
    int t = threadIdx.x;
    const float* xr = x + (size_t)row * N_EMBED;
    float4 v = reinterpret_cast<const float4*>(xr)[t];
    float s = v.x + v.y + v.z + v.w;
    float s2 = v.x * v.x + v.y * v.y + v.z * v.z + v.w * v.w;
#pragma unroll
    for (int m = 1; m < 64; m <<= 1) {
        s += __shfl_xor(s, m);
        s2 += __shfl_xor(s2, m);
    }
    __shared__ float red[8];
    int wv = t >> 6, ln = t & 63;
    if (ln == 0) { red[wv] = s; red[wv + 4] = s2; }
    __syncthreads();
    s = red[0] + red[1] + red[2] + red[3];
    s2 = red[4] + red[5] + red[6] + red[7];
    float mu = s * (1.0f / N_EMBED);
    float var = s2 * (1.0f / N_EMBED) - mu * mu;
    float r = rsqrtf(var + 1e-5f);
    float4 wv4 = reinterpret_cast<const float4*>(w)[t];
    float4 bv4 = reinterpret_cast<const float4*>(b)[t];
    ushort4 o;
    o.x = f2bf((v.x - mu) * r * wv4.x + bv4.x);
    o.y = f2bf((v.y - mu) * r * wv4.y + bv4.y);
    o.z = f2bf((v.z - mu) * r * wv4.z + bv4.z);
    o.w = f2bf((v.w - mu) * r * wv4.w + bv4.w);
    *reinterpret_cast<ushort4*>(out + (size_t)row * N_EMBED + t * 4) = o;
}

// ---------------------------------------------------------------------------
// bf16 GEMM, big-wave-tile (round-9 correctness-proven). BM=WM*128, BN=WN*64,
// WM*WN waves; each wave owns 128x64 (acc[8][4]) -> 32 MFMA : 12 ds_read per
// K-step. BK=32, triple-buffered LDS via global_load_lds, counted
// vmcnt(CALLS) + raw s_barrier, XCD swizzle, source-side XOR chunk swizzle.
// Used ONLY at 512 threads (WM=2, WN=4 -> 256x256): 8 waves = 2/SIMD even at
// 1 block/CU. EPI 0: bf16=acc+bias | 2: bf16=gelu(acc+bias).
// ---------------------------------------------------------------------------
template <int EPI, int WM, int WN>
__global__ __launch_bounds__(WM * WN * 64, 2) void gemm256_kernel(
    const unsigned short* __restrict__ A,   // [M][K] bf16
    const unsigned short* __restrict__ BT,  // [N][K] bf16
    const float* __restrict__ bias,         // [N]
    unsigned short* __restrict__ outb,      // [M][N] bf16
    int M, int N, int K) {
    constexpr int BM = WM * 128;
    constexpr int BN = WN * 64;
    constexpr int T = WM * WN * 64;
    constexpr int CA = BM * 4 / T;   // gll16 calls per thread for A tile
    constexpr int CB = BN * 4 / T;   // ... for B tile
    constexpr int CALLS = CA + CB;
    __shared__ __align__(16) unsigned short As[3][BM * 32];
    __shared__ __align__(16) unsigned short Bs[3][BN * 32];

    int nbn = N / BN;
    int nwg = gridDim.x;
    int orig = blockIdx.x;
    int swz = (orig & 7) * (nwg >> 3) + (orig >> 3);
    int bm = swz / nbn, bn = swz % nbn;
    int t = threadIdx.x;
    int lane = t & 63, wv = t >> 6;
    int wm = wv / WN, wn = wv % WN;
    int mr = lane & 15, kg = lane >> 4;

    f32x4 acc[8][4];
#pragma unroll
    for (int i = 0; i < 8; i++)
#pragma unroll
        for (int j = 0; j < 4; j++) acc[i][j] = (f32x4){0.f, 0.f, 0.f, 0.f};

    // staging: chunk L = c*T + wv*64 + lane -> row L>>2, slot L&3;
    // global source slot XOR'd with (row>>1)&3; LDS dest stays linear.
    const unsigned short* srcA[CA];
    int dstA[CA];
#pragma unroll
    for (int c = 0; c < CA; c++) {
        int L = c * T + wv * 64 + lane;
        int row = L >> 2, slot = L & 3;
        srcA[c] = A + (size_t)(bm * BM + row) * K + (slot ^ ((row >> 1) & 3)) * 8;
        dstA[c] = (c * T + wv * 64) * 8;
    }
    const unsigned short* srcB[CB];
    int dstB[CB];
#pragma unroll
    for (int c = 0; c < CB; c++) {
        int L = c * T + wv * 64 + lane;
        int row = L >> 2, slot = L & 3;
        srcB[c] = BT + (size_t)(bn * BN + row) * K + (slot ^ ((row >> 1) & 3)) * 8;
        dstB[c] = (c * T + wv * 64) * 8;
    }

    auto stage = [&](int ki, int bi) {
        int k0 = ki << 5;
#pragma unroll
        for (int c = 0; c < CA; c++) gll16(srcA[c] + k0, As[bi] + dstA[c]);
#pragma unroll
        for (int c = 0; c < CB; c++) gll16(srcB[c] + k0, Bs[bi] + dstB[c]);
    };

    int nk = K >> 5;
    stage(0, 0);
    stage(1, 1);

    for (int ki = 0; ki < nk; ki++) {
        // my CALLS chunks of tile ki landed; tile ki+1's stay in flight
        if (ki + 1 < nk) {
            asm volatile("s_waitcnt vmcnt(%0)" ::"n"(CALLS) : "memory");
        } else {
            asm volatile("s_waitcnt vmcnt(0)" ::: "memory");
        }
        __builtin_amdgcn_s_barrier();
        if (ki + 2 < nk) stage(ki + 2, (ki + 2) % 3);

        int cur = ki % 3;
        bf16x8 af[8], bfr[4];
#pragma unroll
        for (int i = 0; i < 8; i++) {
            int row = wm * 128 + i * 16 + mr;
            af[i] = *reinterpret_cast<const bf16x8*>(
                &As[cur][row * 32 + ((kg ^ ((row >> 1) & 3)) * 8)]);
        }
#pragma unroll
        for (int j = 0; j < 4; j++) {
            int row = wn * 64 + j * 16 + mr;
            bfr[j] = *reinterpret_cast<const bf16x8*>(
                &Bs[cur][row * 32 + ((kg ^ ((row >> 1) & 3)) * 8)]);
        }
        __builtin_amdgcn_s_setprio(1);
#pragma unroll
        for (int i = 0; i < 8; i++)
#pragma unroll
            for (int j = 0; j < 4; j++)
                acc[i][j] = __builtin_amdgcn_mfma_f32_16x16x32_bf16(af[i], bfr[j], acc[i][j], 0, 0, 0);
        __builtin_amdgcn_s_setprio(0);
    }

#pragma unroll
    for (int i = 0; i < 8; i++)
#pragma unroll
        for (int j = 0; j < 4; j++) {
            int n = bn * BN + wn * 64 + j * 16 + mr;
            float bs = bias[n];
#pragma unroll
            for (int r = 0; r < 4; r++) {
                int m = bm * BM + wm * 128 + i * 16 + kg * 4 + r;
                float v = acc[i][j][r] + bs;
                if (EPI == 2) v = 0.5f * v * (1.0f + erff(v * 0.70710678118f));
                outb[(size_t)m * N + n] = f2bf(v);
            }
        }
}

// ---------------------------------------------------------------------------
// bf16 GEMM (128x128, round-8 proven): triple-buffered global_load_lds,
// counted vmcnt(4) + raw s_barrier, XCD swizzle, source-side chunk swizzle.
// EPI 1: out f32 = acc + bias + resid   (used for wo and proj)
// ---------------------------------------------------------------------------
template <int EPI>
__global__ __launch_bounds__(256) void gemm_kernel(
    const unsigned short* __restrict__ A,   // [M][K] bf16
    const unsigned short* __restrict__ BT,  // [N][K] bf16
    const float* __restrict__ bias,         // [N]
    const float* __restrict__ resid,        // [M][N] fp32 or nullptr
    float* __restrict__ outf,               // [M][N] fp32 (EPI 1)
    unsigned short* __restrict__ outb,      // [M][N] bf16 (EPI 0,2)
    int M, int N, int K) {
    __shared__ __align__(16) unsigned short As[3][128 * 32];
    __shared__ __align__(16) unsigned short Bs[3][128 * 32];
    int nbn = N >> 7;
    int nwg = gridDim.x;
    int orig = blockIdx.x;
    int swz = (orig & 7) * (nwg >> 3) + (orig >> 3);
    int bm = swz / nbn, bn = swz % nbn;
    int t = threadIdx.x;
    int lane = t & 63, wv = t >> 6;
    int wm = wv >> 1, wn = wv & 1;
    int mr = lane & 15, kg = lane >> 4;

    f32x4 acc[4][4];
#pragma unroll
    for (int i = 0; i < 4; i++)
#pragma unroll
        for (int j = 0; j < 4; j++) acc[i][j] = (f32x4){0.f, 0.f, 0.f, 0.f};

    int srow = t >> 2, sq = t & 3;
    int sqs = sq ^ ((srow >> 1) & 3);
    const unsigned short* gA1 = A + (size_t)(bm * 128 + srow) * K + sqs * 8;
    const unsigned short* gA2 = gA1 + (size_t)64 * K;
    const unsigned short* gB1 = BT + (size_t)(bn * 128 + srow) * K + sqs * 8;
    const unsigned short* gB2 = gB1 + (size_t)64 * K;
    int w512 = wv * 512;

    auto stageg = [&](int ki, int bi) {
        int k0 = ki << 5;
        gll16(gA1 + k0, As[bi] + w512);
        gll16(gA2 + k0, As[bi] + 2048 + w512);
        gll16(gB1 + k0, Bs[bi] + w512);
        gll16(gB2 + k0, Bs[bi] + 2048 + w512);
    };

    int nk = K >> 5;
    stageg(0, 0);
    stageg(1, 1);

    const int csw = (mr >> 1) & 3;
    for (int ki = 0; ki < nk; ki++) {
        if (ki + 1 < nk) {
            asm volatile("s_waitcnt vmcnt(4)" ::: "memory");
        } else {
            asm volatile("s_waitcnt vmcnt(0)" ::: "memory");
        }
        __builtin_amdgcn_s_barrier();
        if (ki + 2 < nk) stageg(ki + 2, (ki + 2) % 3);

        int cur = ki % 3;
        bf16x8 af[4], bfr[4];
#pragma unroll
        for (int i = 0; i < 4; i++)
            af[i] = *reinterpret_cast<const bf16x8*>(
                &As[cur][(wm * 64 + i * 16 + mr) * 32 + ((kg ^ csw) * 8)]);
#pragma unroll
        for (int j = 0; j < 4; j++)
            bfr[j] = *reinterpret_cast<const bf16x8*>(
                &Bs[cur][(wn * 64 + j * 16 + mr) * 32 + ((kg ^ csw) * 8)]);
#pragma unroll
        for (int i = 0; i < 4; i++)
#pragma unroll
            for (int j = 0; j < 4; j++)
                acc[i][j] = __builtin_amdgcn_mfma_f32_16x16x32_bf16(af[i], bfr[j], acc[i][j], 0, 0, 0);
    }

#pragma unroll
    for (int i = 0; i < 4; i++)
#pragma unroll
        for (int j = 0; j < 4; j++) {
            int n = bn * 128 + wn * 64 + j * 16 + mr;
            float bs = bias[n];
#pragma unroll
            for (int r = 0; r < 4; r++) {
                int m = bm * 128 + wm * 64 + i * 16 + kg * 4 + r;
                size_t idx = (size_t)m * N + n;
                float v = acc[i][j][r] + bs;
                if (EPI == 0) {
                    outb[idx] = f2bf(v);
                } else if (EPI == 1) {
                    outf[idx] = v + resid[idx];
                } else {
                    float g = 0.5f * v * (1.0f + erff(v * 0.70710678118f));
                    outb[idx] = f2bf(g);
                }
            }
        }
}

// ---------------------------------------------------------------------------
// Flash-style causal attention (round-8 proven). SWAPPED QK^T (S^T = K·Q^T),
// K/V triple-buffered LDS via global_load_lds, counted vmcnt(4) + s_barrier.
// 512 blocks: wid = qp*64 + bh (same-bh blocks share an XCD). Items
// {qt=qp, 15-qp} -> exactly 34 KV-tile iterations per block. LDS 64KB.
// ---------------------------------------------------------------------------
__global__ __launch_bounds__(256) void attn_kernel(
    const unsigned short* __restrict__ qkv,
    const unsigned short* __restrict__ vt,
    unsigned short* __restrict__ ctx) {
    __shared__ __align__(16) unsigned short Kb[3][4096];
    __shared__ __align__(16) unsigned short Vb[3][4096];
    __shared__ __align__(16) unsigned short PT[8192];  // [128 q][64 kv], swizzled
    const float SCL = 0.18033688011112042f;  // 0.125 * log2(e)
    int t = threadIdx.x, lane = t & 63, wv = t >> 6;
    int mr = lane & 15, kg = lane >> 4;

    int wid = blockIdx.x;          // qp*64 + bh
    int bh = wid & 63, qp2 = wid >> 6;
    int h = bh & 15, b = bh >> 4;

    const unsigned short* qptr = qkv + (size_t)(b * TT) * QKV_LD + h * HD;
    const unsigned short* kp = qptr + N_EMBED;
    const unsigned short* vtp = vt + (size_t)bh * HD * TT;

    int srow[2], scol[2], sbase[2];
#pragma unroll
    for (int i = 0; i < 2; i++) {
        int L = i * 256 + wv * 64 + lane;
        int row = L >> 3, slot = L & 7;
        srow[i] = row;
        scol[i] = (slot ^ (row & 7)) * 8;
        sbase[i] = (i * 256 + wv * 64) * 8;
    }
    const int csw = mr & 7;

    auto stage = [&](int tile, int bi) {
        int kv0 = tile * 64;
#pragma unroll
        for (int i = 0; i < 2; i++) {
            gll16(kp + (size_t)(kv0 + srow[i]) * QKV_LD + scol[i], &Kb[bi][sbase[i]]);
            gll16(vtp + (size_t)srow[i] * TT + kv0 + scol[i], &Vb[bi][sbase[i]]);
        }
    };

    for (int item = 0; item < 2; ++item) {
        int qt = (item == 0) ? qp2 : 15 - qp2;
        int ntiles = 2 * qt + 2;
        int qbase = qt * 128 + wv * 32;

        bf16x8 aq[2][2];
#pragma unroll
        for (int f = 0; f < 2; f++)
#pragma unroll
            for (int c = 0; c < 2; c++)
                aq[f][c] = *reinterpret_cast<const bf16x8*>(
                    qptr + (size_t)(qbase + f * 16 + mr) * QKV_LD + c * 32 + kg * 8);

        f32x4 Oa[2][4];
#pragma unroll
        for (int f = 0; f < 2; f++)
#pragma unroll
            for (int jd = 0; jd < 4; jd++) Oa[f][jd] = (f32x4){0.f, 0.f, 0.f, 0.f};
        float mrow[2] = {-3.0e38f, -3.0e38f};
        float lrow[2] = {0.f, 0.f};

        stage(0, 0);
        stage(1, 1);

        for (int tl = 0; tl < ntiles; ++tl) {
            if (tl + 1 < ntiles) {
                asm volatile("s_waitcnt vmcnt(4)" ::: "memory");
            } else {
                asm volatile("s_waitcnt vmcnt(0)" ::: "memory");
            }
            __builtin_amdgcn_s_barrier();
            int t2 = tl + 2;
            if (t2 < ntiles) stage(t2, t2 % 3);

            int bi = tl % 3;
            int kv0 = tl * 64;
            const unsigned short* Kt = Kb[bi];
            const unsigned short* Vt = Vb[bi];

            f32x4 sf[2][4];
#pragma unroll
            for (int j = 0; j < 4; j++) {
                int rl = j * 16 + mr;
                bf16x8 bk0 = *reinterpret_cast<const bf16x8*>(&Kt[rl * 64 + (kg ^ csw) * 8]);
                bf16x8 bk1 = *reinterpret_cast<const bf16x8*>(&Kt[rl * 64 + ((4 + kg) ^ csw) * 8]);
#pragma unroll
                for (int f = 0; f < 2; f++) {
                    f32x4 s = (f32x4){0.f, 0.f, 0.f, 0.f};
                    s = __builtin_amdgcn_mfma_f32_16x16x32_bf16(bk0, aq[f][0], s, 0, 0, 0);
                    s = __builtin_amdgcn_mfma_f32_16x16x32_bf16(bk1, aq[f][1], s, 0, 0, 0);
                    sf[f][j] = s;
                }
            }

            bool dmask = (tl >= 2 * qt);
#pragma unroll
            for (int f = 0; f < 2; f++) {
                int qrow = qbase + f * 16 + mr;
                int R = wv * 32 + f * 16 + mr;
                float mx = -3.0e38f;
#pragma unroll
                for (int j = 0; j < 4; j++)
#pragma unroll
                    for (int r = 0; r < 4; r++) {
                        float sv = sf[f][j][r] * SCL;
                        if (dmask && (kv0 + j * 16 + kg * 4 + r > qrow)) sv = -3.0e38f;
                        sf[f][j][r] = sv;
                        mx = fmaxf(mx, sv);
                    }
                mx = fmaxf(mx, __shfl_xor(mx, 16));
                mx = fmaxf(mx, __shfl_xor(mx, 32));
                float mn = fmaxf(mrow[f], mx);
                float al = __builtin_amdgcn_exp2f(mrow[f] - mn);
                mrow[f] = mn;
#pragma unroll
                for (int jd = 0; jd < 4; jd++) Oa[f][jd] *= al;
                float ps = 0.f;
#pragma unroll
                for (int j = 0; j < 4; j++)
#pragma unroll
                    for (int r = 0; r < 4; r++) {
                        float p = __builtin_amdgcn_exp2f(sf[f][j][r] - mn);
                        sf[f][j][r] = p;
                        ps += p;
                    }
                ps += __shfl_xor(ps, 16);
                ps += __shfl_xor(ps, 32);
                lrow[f] = lrow[f] * al + ps;
                int rsw = R & 7;
#pragma unroll
                for (int j = 0; j < 4; j++) {
                    unsigned lo = (unsigned)f2bf(sf[f][j][0]) | ((unsigned)f2bf(sf[f][j][1]) << 16);
                    unsigned hi = (unsigned)f2bf(sf[f][j][2]) | ((unsigned)f2bf(sf[f][j][3]) << 16);
                    int cw = 2 * j + (kg >> 1);
                    int addr = R * 64 + ((cw ^ rsw) << 3) + (kg & 1) * 4;
                    uint2 pk; pk.x = lo; pk.y = hi;
                    *reinterpret_cast<uint2*>(&PT[addr]) = pk;
                }
            }

#pragma unroll
            for (int c = 0; c < 2; c++) {
                int R0 = wv * 32 + mr, R1 = R0 + 16;
                bf16x8 pb0 = *reinterpret_cast<const bf16x8*>(
                    &PT[R0 * 64 + (((c * 4 + kg) ^ (R0 & 7)) << 3)]);
                bf16x8 pb1 = *reinterpret_cast<const bf16x8*>(
                    &PT[R1 * 64 + (((c * 4 + kg) ^ (R1 & 7)) << 3)]);
#pragma unroll
                for (int jd = 0; jd < 4; jd++) {
                    int rv = jd * 16 + mr;
                    bf16x8 vf = *reinterpret_cast<const bf16x8*>(
                        &Vt[rv * 64 + (((c * 4 + kg) ^ (rv & 7)) << 3)]);
                    Oa[0][jd] = __builtin_amdgcn_mfma_f32_16x16x32_bf16(vf, pb0, Oa[0][jd], 0, 0, 0);
                    Oa[1][jd] = __builtin_amdgcn_mfma_f32_16x16x32_bf16(vf, pb1, Oa[1][jd], 0, 0, 0);
                }
            }
        }

#pragma unroll
        for (int f = 0; f < 2; f++) {
            float iv = 1.0f / lrow[f];
            int q = qbase + f * 16 + mr;
#pragma unroll
            for (int jd = 0; jd < 4; jd++) {
                ushort4 o;
                o.x = f2bf(Oa[f][jd][0] * iv);
                o.y = f2bf(Oa[f][jd][1] * iv);
                o.z = f2bf(Oa[f][jd][2] * iv);
                o.w = f2bf(Oa[f][jd][3] * iv);
                *reinterpret_cast<ushort4*>(
                    ctx + (size_t)(b * TT + q) * N_EMBED + h * HD + jd * 16 + kg * 4) = o;
            }
        }
        __syncthreads();
    }
}

// ---------------------------------------------------------------------------
extern "C" void kernel_launch(void* const* d_in, const int* in_sizes, int n_in,
                              void* d_out, int out_size, void* d_ws, size_t ws_size,
                              hipStream_t stream) {
    const float* x      = (const float*)d_in[0];
    const float* ln1_w  = (const float*)d_in[1];
    const float* ln1_b  = (const float*)d_in[2];
    const float* w_qkv  = (const float*)d_in[3];
    const float* b_qkv  = (const float*)d_in[4];
    const float* w_o    = (const float*)d_in[5];
    const float* b_o    = (const float*)d_in[6];
    const float* ln2_w  = (const float*)d_in[7];
    const float* ln2_b  = (const float*)d_in[8];
    const float* w_fc   = (const float*)d_in[9];
    const float* b_fc   = (const float*)d_in[10];
    const float* w_proj = (const float*)d_in[11];
    const float* b_proj = (const float*)d_in[12];
    float* out = (float*)d_out;

    char* ws = (char*)d_ws;
    size_t off = 0;
    auto alloc = [&](size_t bytes) -> void* {
        void* p = ws + off;
        off += (bytes + 255) & ~(size_t)255;
        return p;
    };
    unsigned short* wqkv_t  = (unsigned short*)alloc((size_t)3072 * 1024 * 2);
    unsigned short* wo_t    = (unsigned short*)alloc((size_t)1024 * 1024 * 2);
    unsigned short* wfc_t   = (unsigned short*)alloc((size_t)4096 * 1024 * 2);
    unsigned short* wproj_t = (unsigned short*)alloc((size_t)1024 * 4096 * 2);
    unsigned short* lnb     = (unsigned short*)alloc((size_t)NTOK * 1024 * 2);
    float*          x1      = (float*)alloc((size_t)NTOK * 1024 * 4);
    unsigned short* qkv     = (unsigned short*)alloc((size_t)NTOK * 3072 * 2);
    unsigned short* ctxb    = (unsigned short*)alloc((size_t)NTOK * 1024 * 2);
    unsigned short* hbuf    = qkv;                 // overlays qkv (dead after attn)
    unsigned short* vt      = (unsigned short*)x1; // overlays x1 (written after attn)

    dim3 tb32(32, 8);
    transpose_bf16_kernel<<<dim3(3072 / 32, 1024 / 32), tb32, 0, stream>>>(w_qkv, wqkv_t, 1024, 3072);
    transpose_bf16_kernel<<<dim3(1024 / 32, 1024 / 32), tb32, 0, stream>>>(w_o, wo_t, 1024, 1024);
    transpose_bf16_kernel<<<dim3(4096 / 32, 1024 / 32), tb32, 0, stream>>>(w_fc, wfc_t, 1024, 4096);
    transpose_bf16_kernel<<<dim3(1024 / 32, 4096 / 32), tb32, 0, stream>>>(w_proj, wproj_t, 4096, 1024);

    // ln1(x) -> lnb
    ln_kernel<<<NTOK, 256, 0, stream>>>(x, ln1_w, ln1_b, lnb);
    // qkv = lnb @ w_qkv + b_qkv   (256x256 big-tile, 512 thr, grid 384)
    gemm256_kernel<0, 2, 4><<<(NTOK / 256) * (3072 / 256), 512, 0, stream>>>(
        lnb, wqkv_t, b_qkv, qkv, NTOK, 3072, 1024);
    // V transpose -> vt
    transpose_v_kernel<<<dim3(TT / 32, HD / 32, BB * N_HEAD), tb32, 0, stream>>>(qkv, vt);
    // attention -> ctx  (512 blocks, bh-major XCD grouping, LPT-paired)
    attn_kernel<<<512, 256, 0, stream>>>(qkv, vt, ctxb);
    // x1 = ctx @ w_o + b_o + x   (128^2 proven; x1 overwrites vt — dead now)
    gemm_kernel<1><<<(NTOK / 128) * (1024 / 128), 256, 0, stream>>>(
        ctxb, wo_t, b_o, x, x1, nullptr, NTOK, 1024, 1024);
    // ln2(x1) -> lnb
    ln_kernel<<<NTOK, 256, 0, stream>>>(x1, ln2_w, ln2_b, lnb);
    // h = gelu(lnb @ w_fc + b_fc)   (256x256 big-tile, 512 thr, grid 512)
    gemm256_kernel<2, 2, 4><<<(NTOK / 256) * (4096 / 256), 512, 0, stream>>>(
        lnb, wfc_t, b_fc, hbuf, NTOK, 4096, 1024);
    // out = h @ w_proj + b_proj + x1   (128^2 proven)
    gemm_kernel<1><<<(NTOK / 128) * (1024 / 128), 256, 0, stream>>>(
        hbuf, wproj_t, b_proj, x1, out, nullptr, NTOK, 1024, 4096);
}

// Round 18
// 425.102 us; speedup vs baseline: 1.0898x; 1.0898x over previous
//
#include <hip/hip_runtime.h>
#include <hip/hip_bf16.h>
#include <math.h>

#define N_EMBED 1024
#define N_HEAD 16
#define HD 64
#define BB 4
#define TT 2048
#define NTOK (BB * TT)        // 8192 rows
#define QKV_LD (3 * N_EMBED)  // 3072

typedef __bf16 bf16x8 __attribute__((ext_vector_type(8)));
typedef float f32x4 __attribute__((ext_vector_type(4)));

__device__ __forceinline__ unsigned short f2bf(float f) {
    __hip_bfloat16 h = __float2bfloat16(f);
    return __builtin_bit_cast(unsigned short, h);
}

// async global->LDS, 16B per lane. LDS dest = wave-uniform base + lane*16.
__device__ __forceinline__ void gll16(const unsigned short* g, unsigned short* l) {
    __builtin_amdgcn_global_load_lds(
        (const __attribute__((address_space(1))) void*)g,
        (__attribute__((address_space(3))) void*)l,
        16, 0, 0);
}

// ---------------------------------------------------------------------------
// Weight transpose + fp32 -> bf16 convert:  in [K][N] fp32  ->  out [N][K] bf16
// ---------------------------------------------------------------------------
__global__ __launch_bounds__(256) void transpose_bf16_kernel(
    const float* __restrict__ in, unsigned short* __restrict__ out, int K, int N) {
    __shared__ float tile[32][33];
    int bx = blockIdx.x * 32;  // n base
    int by = blockIdx.y * 32;  // k base
    int tx = threadIdx.x, ty = threadIdx.y;
#pragma unroll
    for (int i = ty; i < 32; i += 8)
        tile[i][tx] = in[(size_t)(by + i) * N + bx + tx];
    __syncthreads();
#pragma unroll
    for (int i = ty; i < 32; i += 8)
        out[(size_t)(bx + i) * K + by + tx] = f2bf(tile[tx][i]);
}

// ---------------------------------------------------------------------------
// V transpose: qkv [B*T][3072] (v at col 2048+h*64) -> vt [b*16+h][64][2048]
// ---------------------------------------------------------------------------
__global__ __launch_bounds__(256) void transpose_v_kernel(
    const unsigned short* __restrict__ qkv, unsigned short* __restrict__ vt) {
    __shared__ unsigned short tile[32][33];
    int z = blockIdx.z;
    int b = z >> 4, h = z & 15;
    int t0 = blockIdx.x * 32, d0 = blockIdx.y * 32;
    int tx = threadIdx.x, ty = threadIdx.y;
    const unsigned short* src = qkv + (size_t)(b * TT) * QKV_LD + 2 * N_EMBED + h * HD;
#pragma unroll
    for (int i = ty; i < 32; i += 8)
        tile[i][tx] = src[(size_t)(t0 + i) * QKV_LD + d0 + tx];
    __syncthreads();
    unsigned short* dst = vt + (size_t)z * HD * TT;
#pragma unroll
    for (int i = ty; i < 32; i += 8)
        dst[(size_t)(d0 + i) * TT + t0 + tx] = tile[tx][i];
}

// ---------------------------------------------------------------------------
// Row LayerNorm: fp32 in [rows][1024] -> bf16 out
// ---------------------------------------------------------------------------
__global__ __launch_bounds__(256) void ln_kernel(
    const float* __restrict__ x, const float* __restrict__ w,
    const float* __restrict__ b, unsigned short* __restrict__ out) {
    int row = blockIdx.x;
    int t = threadIdx.x;
    const float* xr = x + (size_t)row * N_EMBED;
    float4 v = reinterpret_cast<const float4*>(xr)[t];
    float s = v.x + v.y + v.z + v.w;
    float s2 = v.x * v.x + v.y * v.y + v.z * v.z + v.w * v.w;
#pragma unroll
    for (int m = 1; m < 64; m <<= 1) {
        s += __shfl_xor(s, m);
        s2 += __shfl_xor(s2, m);
    }
    __shared__ float red[8];
    int wv = t >> 6, ln = t & 63;
    if (ln == 0) { red[wv] = s; red[wv + 4] = s2; }
    __syncthreads();
    s = red[0] + red[1] + red[2] + red[3];
    s2 = red[4] + red[5] + red[6] + red[7];
    float mu = s * (1.0f / N_EMBED);
    float var = s2 * (1.0f / N_EMBED) - mu * mu;
    float r = rsqrtf(var + 1e-5f);
    float4 wv4 = reinterpret_cast<const float4*>(w)[t];
    float4 bv4 = reinterpret_cast<const float4*>(b)[t];
    ushort4 o;
    o.x = f2bf((v.x - mu) * r * wv4.x + bv4.x);
    o.y = f2bf((v.y - mu) * r * wv4.y + bv4.y);
    o.z = f2bf((v.z - mu) * r * wv4.z + bv4.z);
    o.w = f2bf((v.w - mu) * r * wv4.w + bv4.w);
    *reinterpret_cast<ushort4*>(out + (size_t)row * N_EMBED + t * 4) = o;
}

// ---------------------------------------------------------------------------
// bf16 GEMM: C[M][N] = A[M][K] @ BT[N][K]^T + bias. 128x128 tile, BK=32,
// TRIPLE-buffered LDS staging via global_load_lds with counted vmcnt(4) +
// raw s_barrier (tile t+1/t+2 stay in flight across the barrier), XCD
// swizzle, source-side XOR chunk swizzle (conflict-free, measured 0).
// EPI 0: bf16 = acc+bias | 1: f32 = acc+bias+resid | 2: bf16 = gelu(acc+bias)
// ---------------------------------------------------------------------------
template <int EPI>
__global__ __launch_bounds__(256) void gemm_kernel(
    const unsigned short* __restrict__ A,   // [M][K] bf16
    const unsigned short* __restrict__ BT,  // [N][K] bf16
    const float* __restrict__ bias,         // [N]
    const float* __restrict__ resid,        // [M][N] fp32 or nullptr
    float* __restrict__ outf,               // [M][N] fp32 (EPI 1)
    unsigned short* __restrict__ outb,      // [M][N] bf16 (EPI 0,2)
    int M, int N, int K) {
    __shared__ __align__(16) unsigned short As[3][128 * 32];
    __shared__ __align__(16) unsigned short Bs[3][128 * 32];
    int nbn = N >> 7;
    int nwg = gridDim.x;
    int orig = blockIdx.x;
    int swz = (orig & 7) * (nwg >> 3) + (orig >> 3);
    int bm = swz / nbn, bn = swz % nbn;
    int t = threadIdx.x;
    int lane = t & 63, wv = t >> 6;
    int wm = wv >> 1, wn = wv & 1;
    int mr = lane & 15, kg = lane >> 4;

    f32x4 acc[4][4];
#pragma unroll
    for (int i = 0; i < 4; i++)
#pragma unroll
        for (int j = 0; j < 4; j++) acc[i][j] = (f32x4){0.f, 0.f, 0.f, 0.f};

    int srow = t >> 2, sq = t & 3;
    int sqs = sq ^ ((srow >> 1) & 3);
    const unsigned short* gA1 = A + (size_t)(bm * 128 + srow) * K + sqs * 8;
    const unsigned short* gA2 = gA1 + (size_t)64 * K;
    const unsigned short* gB1 = BT + (size_t)(bn * 128 + srow) * K + sqs * 8;
    const unsigned short* gB2 = gB1 + (size_t)64 * K;
    int w512 = wv * 512;

    auto stageg = [&](int ki, int bi) {
        int k0 = ki << 5;
        gll16(gA1 + k0, As[bi] + w512);
        gll16(gA2 + k0, As[bi] + 2048 + w512);
        gll16(gB1 + k0, Bs[bi] + w512);
        gll16(gB2 + k0, Bs[bi] + 2048 + w512);
    };

    int nk = K >> 5;
    stageg(0, 0);
    stageg(1, 1);

    const int csw = (mr >> 1) & 3;
    for (int ki = 0; ki < nk; ki++) {
        if (ki + 1 < nk) {
            asm volatile("s_waitcnt vmcnt(4)" ::: "memory");
        } else {
            asm volatile("s_waitcnt vmcnt(0)" ::: "memory");
        }
        __builtin_amdgcn_s_barrier();
        if (ki + 2 < nk) stageg(ki + 2, (ki + 2) % 3);

        int cur = ki % 3;
        bf16x8 af[4], bfr[4];
#pragma unroll
        for (int i = 0; i < 4; i++)
            af[i] = *reinterpret_cast<const bf16x8*>(
                &As[cur][(wm * 64 + i * 16 + mr) * 32 + ((kg ^ csw) * 8)]);
#pragma unroll
        for (int j = 0; j < 4; j++)
            bfr[j] = *reinterpret_cast<const bf16x8*>(
                &Bs[cur][(wn * 64 + j * 16 + mr) * 32 + ((kg ^ csw) * 8)]);
#pragma unroll
        for (int i = 0; i < 4; i++)
#pragma unroll
            for (int j = 0; j < 4; j++)
                acc[i][j] = __builtin_amdgcn_mfma_f32_16x16x32_bf16(af[i], bfr[j], acc[i][j], 0, 0, 0);
    }

#pragma unroll
    for (int i = 0; i < 4; i++)
#pragma unroll
        for (int j = 0; j < 4; j++) {
            int n = bn * 128 + wn * 64 + j * 16 + mr;
            float bs = bias[n];
#pragma unroll
            for (int r = 0; r < 4; r++) {
                int m = bm * 128 + wm * 64 + i * 16 + kg * 4 + r;
                size_t idx = (size_t)m * N + n;
                float v = acc[i][j][r] + bs;
                if (EPI == 0) {
                    outb[idx] = f2bf(v);
                } else if (EPI == 1) {
                    outf[idx] = v + resid[idx];
                } else {
                    float g = 0.5f * v * (1.0f + erff(v * 0.70710678118f));
                    outb[idx] = f2bf(g);
                }
            }
        }
}

// ---------------------------------------------------------------------------
// Flash-style causal attention, SWAPPED QK^T (S^T = K·Q^T) so each lane owns
// one q-row: softmax reduce = in-lane + 2 shfl; P^T written as ds_write_b64,
// read back as ds_read_b128 B-frags. K/V triple-buffered LDS via
// global_load_lds, counted vmcnt(4) + raw s_barrier.
// 512 blocks: wid = qp*64 + bh so a bh's 8 blocks share an XCD (L2-resident
// K/V). Items {qt=qp, 15-qp} -> exactly 34 KV-tile iterations per block.
// LDS: K 3x8KB + V 3x8KB + P^T 16KB = 64KB -> 2 blocks/CU.
// ---------------------------------------------------------------------------
__global__ __launch_bounds__(256) void attn_kernel(
    const unsigned short* __restrict__ qkv,
    const unsigned short* __restrict__ vt,
    unsigned short* __restrict__ ctx) {
    __shared__ __align__(16) unsigned short Kb[3][4096];
    __shared__ __align__(16) unsigned short Vb[3][4096];
    __shared__ __align__(16) unsigned short PT[8192];  // [128 q][64 kv], swizzled
    const float SCL = 0.18033688011112042f;  // 0.125 * log2(e)
    int t = threadIdx.x, lane = t & 63, wv = t >> 6;
    int mr = lane & 15, kg = lane >> 4;

    int wid = blockIdx.x;          // qp*64 + bh  (same-bh blocks = same XCD)
    int bh = wid & 63, qp2 = wid >> 6;
    int h = bh & 15, b = bh >> 4;

    const unsigned short* qptr = qkv + (size_t)(b * TT) * QKV_LD + h * HD;
    const unsigned short* kp = qptr + N_EMBED;
    const unsigned short* vtp = vt + (size_t)bh * HD * TT;

    // staging geometry: call i covers 16B-chunks i*256 + wv*64 + lane
    int srow[2], scol[2], sbase[2];
#pragma unroll
    for (int i = 0; i < 2; i++) {
        int L = i * 256 + wv * 64 + lane;
        int row = L >> 3, slot = L & 7;
        srow[i] = row;
        scol[i] = (slot ^ (row & 7)) * 8;    // pre-swizzled global source chunk
        sbase[i] = (i * 256 + wv * 64) * 8;  // wave-uniform LDS base (ushorts)
    }
    const int csw = mr & 7;  // read-side chunk XOR (row & 7, rows = *16 + mr)

    auto stage = [&](int tile, int bi) {
        int kv0 = tile * 64;
#pragma unroll
        for (int i = 0; i < 2; i++) {
            gll16(kp + (size_t)(kv0 + srow[i]) * QKV_LD + scol[i], &Kb[bi][sbase[i]]);
            gll16(vtp + (size_t)srow[i] * TT + kv0 + scol[i], &Vb[bi][sbase[i]]);
        }
    };

    for (int item = 0; item < 2; ++item) {
        int qt = (item == 0) ? qp2 : 15 - qp2;
        int ntiles = 2 * qt + 2;
        int qbase = qt * 128 + wv * 32;

        // Q as B-operand: col n = mr -> q-row qbase+f*16+mr, k = c*32+kg*8+e
        bf16x8 aq[2][2];
#pragma unroll
        for (int f = 0; f < 2; f++)
#pragma unroll
            for (int c = 0; c < 2; c++)
                aq[f][c] = *reinterpret_cast<const bf16x8*>(
                    qptr + (size_t)(qbase + f * 16 + mr) * QKV_LD + c * 32 + kg * 8);

        // O^T accumulators: col = q = mr, row = d = jd*16 + kg*4 + r
        f32x4 Oa[2][4];
#pragma unroll
        for (int f = 0; f < 2; f++)
#pragma unroll
            for (int jd = 0; jd < 4; jd++) Oa[f][jd] = (f32x4){0.f, 0.f, 0.f, 0.f};
        float mrow[2] = {-3.0e38f, -3.0e38f};
        float lrow[2] = {0.f, 0.f};

        stage(0, 0);
        stage(1, 1);

        for (int tl = 0; tl < ntiles; ++tl) {
            if (tl + 1 < ntiles) {
                asm volatile("s_waitcnt vmcnt(4)" ::: "memory");
            } else {
                asm volatile("s_waitcnt vmcnt(0)" ::: "memory");
            }
            __builtin_amdgcn_s_barrier();
            int t2 = tl + 2;
            if (t2 < ntiles) stage(t2, t2 % 3);

            int bi = tl % 3;
            int kv0 = tl * 64;
            const unsigned short* Kt = Kb[bi];
            const unsigned short* Vt = Vb[bi];

            // S^T = K·Q^T : lane holds S[q=qbase+f*16+mr][kv=kv0+j*16+kg*4+r]
            f32x4 sf[2][4];
#pragma unroll
            for (int j = 0; j < 4; j++) {
                int rl = j * 16 + mr;
                bf16x8 bk0 = *reinterpret_cast<const bf16x8*>(&Kt[rl * 64 + (kg ^ csw) * 8]);
                bf16x8 bk1 = *reinterpret_cast<const bf16x8*>(&Kt[rl * 64 + ((4 + kg) ^ csw) * 8]);
#pragma unroll
                for (int f = 0; f < 2; f++) {
                    f32x4 s = (f32x4){0.f, 0.f, 0.f, 0.f};
                    s = __builtin_amdgcn_mfma_f32_16x16x32_bf16(bk0, aq[f][0], s, 0, 0, 0);
                    s = __builtin_amdgcn_mfma_f32_16x16x32_bf16(bk1, aq[f][1], s, 0, 0, 0);
                    sf[f][j] = s;
                }
            }

            bool dmask = (tl >= 2 * qt);  // only last two tiles touch the diagonal
#pragma unroll
            for (int f = 0; f < 2; f++) {
                int qrow = qbase + f * 16 + mr;
                int R = wv * 32 + f * 16 + mr;
                // scale + mask + in-lane max over this lane's 16 kv values
                float mx = -3.0e38f;
#pragma unroll
                for (int j = 0; j < 4; j++)
#pragma unroll
                    for (int r = 0; r < 4; r++) {
                        float sv = sf[f][j][r] * SCL;
                        if (dmask && (kv0 + j * 16 + kg * 4 + r > qrow)) sv = -3.0e38f;
                        sf[f][j][r] = sv;
                        mx = fmaxf(mx, sv);
                    }
                mx = fmaxf(mx, __shfl_xor(mx, 16));
                mx = fmaxf(mx, __shfl_xor(mx, 32));
                float mn = fmaxf(mrow[f], mx);
                float al = __builtin_amdgcn_exp2f(mrow[f] - mn);
                mrow[f] = mn;
#pragma unroll
                for (int jd = 0; jd < 4; jd++) Oa[f][jd] *= al;
                float ps = 0.f;
#pragma unroll
                for (int j = 0; j < 4; j++)
#pragma unroll
                    for (int r = 0; r < 4; r++) {
                        float p = __builtin_amdgcn_exp2f(sf[f][j][r] - mn);
                        sf[f][j][r] = p;
                        ps += p;
                    }
                ps += __shfl_xor(ps, 16);
                ps += __shfl_xor(ps, 32);
                lrow[f] = lrow[f] * al + ps;
                // P^T -> LDS: 4 consecutive kv per (j): ds_write_b64, swizzled
                int rsw = R & 7;
#pragma unroll
                for (int j = 0; j < 4; j++) {
                    unsigned lo = (unsigned)f2bf(sf[f][j][0]) | ((unsigned)f2bf(sf[f][j][1]) << 16);
                    unsigned hi = (unsigned)f2bf(sf[f][j][2]) | ((unsigned)f2bf(sf[f][j][3]) << 16);
                    int cw = 2 * j + (kg >> 1);
                    int addr = R * 64 + ((cw ^ rsw) << 3) + (kg & 1) * 4;
                    uint2 pk; pk.x = lo; pk.y = hi;
                    *reinterpret_cast<uint2*>(&PT[addr]) = pk;
                }
            }

            // O^T += V^T · P^T  (V^T as A: row=d=jd*16+mr; P^T as B: col=q=mr)
#pragma unroll
            for (int c = 0; c < 2; c++) {
                int R0 = wv * 32 + mr, R1 = R0 + 16;
                bf16x8 pb0 = *reinterpret_cast<const bf16x8*>(
                    &PT[R0 * 64 + (((c * 4 + kg) ^ (R0 & 7)) << 3)]);
                bf16x8 pb1 = *reinterpret_cast<const bf16x8*>(
                    &PT[R1 * 64 + (((c * 4 + kg) ^ (R1 & 7)) << 3)]);
#pragma unroll
                for (int jd = 0; jd < 4; jd++) {
                    int rv = jd * 16 + mr;
                    bf16x8 vf = *reinterpret_cast<const bf16x8*>(
                        &Vt[rv * 64 + (((c * 4 + kg) ^ (rv & 7)) << 3)]);
                    Oa[0][jd] = __builtin_amdgcn_mfma_f32_16x16x32_bf16(vf, pb0, Oa[0][jd], 0, 0, 0);
                    Oa[1][jd] = __builtin_amdgcn_mfma_f32_16x16x32_bf16(vf, pb1, Oa[1][jd], 0, 0, 0);
                }
            }
        }

        // epilogue: ctx[q][h*64+d] = O/l ; lane writes 4 consecutive d (8B)
#pragma unroll
        for (int f = 0; f < 2; f++) {
            float iv = 1.0f / lrow[f];
            int q = qbase + f * 16 + mr;
#pragma unroll
            for (int jd = 0; jd < 4; jd++) {
                ushort4 o;
                o.x = f2bf(Oa[f][jd][0] * iv);
                o.y = f2bf(Oa[f][jd][1] * iv);
                o.z = f2bf(Oa[f][jd][2] * iv);
                o.w = f2bf(Oa[f][jd][3] * iv);
                *reinterpret_cast<ushort4*>(
                    ctx + (size_t)(b * TT + q) * N_EMBED + h * HD + jd * 16 + kg * 4) = o;
            }
        }
        __syncthreads();  // buffers free before next item's prologue staging
    }
}

// ---------------------------------------------------------------------------
extern "C" void kernel_launch(void* const* d_in, const int* in_sizes, int n_in,
                              void* d_out, int out_size, void* d_ws, size_t ws_size,
                              hipStream_t stream) {
    const float* x      = (const float*)d_in[0];
    const float* ln1_w  = (const float*)d_in[1];
    const float* ln1_b  = (const float*)d_in[2];
    const float* w_qkv  = (const float*)d_in[3];
    const float* b_qkv  = (const float*)d_in[4];
    const float* w_o    = (const float*)d_in[5];
    const float* b_o    = (const float*)d_in[6];
    const float* ln2_w  = (const float*)d_in[7];
    const float* ln2_b  = (const float*)d_in[8];
    const float* w_fc   = (const float*)d_in[9];
    const float* b_fc   = (const float*)d_in[10];
    const float* w_proj = (const float*)d_in[11];
    const float* b_proj = (const float*)d_in[12];
    float* out = (float*)d_out;

    char* ws = (char*)d_ws;
    size_t off = 0;
    auto alloc = [&](size_t bytes) -> void* {
        void* p = ws + off;
        off += (bytes + 255) & ~(size_t)255;
        return p;
    };
    unsigned short* wqkv_t  = (unsigned short*)alloc((size_t)3072 * 1024 * 2);
    unsigned short* wo_t    = (unsigned short*)alloc((size_t)1024 * 1024 * 2);
    unsigned short* wfc_t   = (unsigned short*)alloc((size_t)4096 * 1024 * 2);
    unsigned short* wproj_t = (unsigned short*)alloc((size_t)1024 * 4096 * 2);
    unsigned short* lnb     = (unsigned short*)alloc((size_t)NTOK * 1024 * 2);
    float*          x1      = (float*)alloc((size_t)NTOK * 1024 * 4);
    unsigned short* qkv     = (unsigned short*)alloc((size_t)NTOK * 3072 * 2);
    unsigned short* ctxb    = (unsigned short*)alloc((size_t)NTOK * 1024 * 2);
    unsigned short* hbuf    = qkv;                 // overlays qkv (dead after attn)
    unsigned short* vt      = (unsigned short*)x1; // overlays x1 (written after attn)

    dim3 tb32(32, 8);
    transpose_bf16_kernel<<<dim3(3072 / 32, 1024 / 32), tb32, 0, stream>>>(w_qkv, wqkv_t, 1024, 3072);
    transpose_bf16_kernel<<<dim3(1024 / 32, 1024 / 32), tb32, 0, stream>>>(w_o, wo_t, 1024, 1024);
    transpose_bf16_kernel<<<dim3(4096 / 32, 1024 / 32), tb32, 0, stream>>>(w_fc, wfc_t, 1024, 4096);
    transpose_bf16_kernel<<<dim3(1024 / 32, 4096 / 32), tb32, 0, stream>>>(w_proj, wproj_t, 4096, 1024);

    // ln1(x) -> lnb
    ln_kernel<<<NTOK, 256, 0, stream>>>(x, ln1_w, ln1_b, lnb);
    // qkv = lnb @ w_qkv + b_qkv
    gemm_kernel<0><<<(NTOK / 128) * (3072 / 128), 256, 0, stream>>>(
        lnb, wqkv_t, b_qkv, nullptr, nullptr, qkv, NTOK, 3072, 1024);
    // V transpose -> vt
    transpose_v_kernel<<<dim3(TT / 32, HD / 32, BB * N_HEAD), tb32, 0, stream>>>(qkv, vt);
    // attention -> ctx  (512 blocks, bh-major XCD grouping, LPT-paired)
    attn_kernel<<<512, 256, 0, stream>>>(qkv, vt, ctxb);
    // x1 = ctx @ w_o + b_o + x   (x1 overwrites vt region — vt dead now)
    gemm_kernel<1><<<(NTOK / 128) * (1024 / 128), 256, 0, stream>>>(
        ctxb, wo_t, b_o, x, x1, nullptr, NTOK, 1024, 1024);
    // ln2(x1) -> lnb
    ln_kernel<<<NTOK, 256, 0, stream>>>(x1, ln2_w, ln2_b, lnb);
    // h = gelu(lnb @ w_fc + b_fc)
    gemm_kernel<2><<<(NTOK / 128) * (4096 / 128), 256, 0, stream>>>(
        lnb, wfc_t, b_fc, nullptr, nullptr, hbuf, NTOK, 4096, 1024);
    // out = h @ w_proj + b_proj + x1
    gemm_kernel<1><<<(NTOK / 128) * (1024 / 128), 256, 0, stream>>>(
        hbuf, wproj_t, b_proj, x1, out, nullptr, NTOK, 1024, 4096);
}